// Round 4
// baseline (538812.012 us; speedup 1.0000x reference)
//
#include <hip/hip_runtime.h>
#include <math.h>

#define TT 1024
#define BB 64
#define HH 512
#define G4 2048            // 4*HH
#define NBLK 256
#define NTHR 1024          // 16 waves
#define KH (HH * BB)       // one [512][64] slab = 32768 elems

// out layout: seq [T][B][H] | h_n [L][B][H] | c_n [L][B][H]
#define HN_OFF ((size_t)TT * BB * HH)
#define CN_OFF (HN_OFF + (size_t)2 * BB * HH)

typedef float v2f __attribute__((ext_vector_type(2)));

__device__ inline float sigm(float v) {
    return 1.0f / (1.0f + __expf(-v));
}
__device__ inline float tanh_fast(float v) {
    const float e = __expf(2.0f * v);
    return 1.0f - 2.0f / (e + 1.0f);
}

// Coherent store: lands at the L3 coherence point so other XCDs can see it
// after their per-step acquire fence.
__device__ inline void store_coh(float* p, float v) {
    __hip_atomic_store(p, v, __ATOMIC_RELAXED, __HIP_MEMORY_SCOPE_AGENT);
}

// ---------------- phase A: transpose x [T][B][K] -> xT [T][K][B] ------------
extern "C" __global__ void __launch_bounds__(256)
xpose(const float* __restrict__ x, float* __restrict__ xT)
{
    __shared__ float tile[64][65];
    const int t   = blockIdx.x;
    const int kc  = blockIdx.y << 6;
    const int tid = threadIdx.x;

    const int kk = tid & 63;
    const int b0 = tid >> 6;
    const float* xp = x + (size_t)t * BB * HH;
    #pragma unroll
    for (int i = 0; i < 16; ++i) {
        const int b = b0 + (i << 2);
        tile[b][kk] = xp[(size_t)b * HH + kc + kk];
    }
    __syncthreads();
    const int b  = tid & 63;
    const int k0 = tid >> 6;
    float* xo = xT + (size_t)t * KH + (size_t)kc * BB;
    #pragma unroll
    for (int i = 0; i < 16; ++i) {
        const int kl = k0 + (i << 2);
        xo[kl * BB + b] = tile[b][kl];
    }
}

// ---------------- grid barrier: relaxed atomics, ONE buffer_inv per step ----
__device__ inline void grid_barrier(unsigned* gbar, unsigned* groot,
                                    unsigned barIdx, int bid)
{
    __syncthreads();   // rendezvous + drains every wave's vmcnt (h-stores done)
    if (threadIdx.x == 0) {
        const int g = bid & 15;
        const unsigned old = __hip_atomic_fetch_add(
            &gbar[g * 16], 1u, __ATOMIC_RELAXED, __HIP_MEMORY_SCOPE_AGENT);
        if (old == barIdx * 16u + 15u) {
            __hip_atomic_fetch_add(groot, 1u, __ATOMIC_RELAXED,
                                   __HIP_MEMORY_SCOPE_AGENT);
        }
        const unsigned tgt = (barIdx + 1u) * 16u;
        while (__hip_atomic_load(groot, __ATOMIC_RELAXED,
                                 __HIP_MEMORY_SCOPE_AGENT) < tgt) {
            __builtin_amdgcn_s_sleep(1);
        }
        // single L1+L2 invalidate for this CU/XCD, per step
        __builtin_amdgcn_fence(__ATOMIC_ACQUIRE, "agent");
    }
    __syncthreads();
}

// issue 16 scalar act loads (one chunk) into a register buffer
#define LOADC(BUF, PTR, J0)                                        \
    _Pragma("unroll")                                              \
    for (int r_ = 0; r_ < 16; ++r_) BUF[r_] = (PTR)[((J0) + r_) * BB];

// consume one 16-k chunk: k-paired pk-fma, no lane duplication
#define FMAC(BUF, J0)                                              \
    _Pragma("unroll")                                              \
    for (int jj_ = 0; jj_ < 4; ++jj_) {                            \
        const v2f aA_ = {BUF[4*jj_ + 0], BUF[4*jj_ + 1]};          \
        const v2f aB_ = {BUF[4*jj_ + 2], BUF[4*jj_ + 3]};          \
        _Pragma("unroll")                                          \
        for (int rr_ = 0; rr_ < 8; ++rr_) {                        \
            const float4 wv_ = *(const float4*)(wl + rr_*128 + (J0) + 4*jj_); \
            acc2[rr_] = __builtin_elementwise_fma(aA_, (v2f){wv_.x, wv_.y}, acc2[rr_]); \
            acc2[rr_] = __builtin_elementwise_fma(aB_, (v2f){wv_.z, wv_.w}, acc2[rr_]); \
        }                                                          \
    }

// ---------------- phase B: pipelined persistent scan ------------------------
// 256 blocks x 16 waves. Block owns 2 hidden units per layer (8 gate rows each),
// chosen via an XCD-bijective swizzle so one XCD owns 64 contiguous units.
// Step s: L0 computes t0=s (s<TT), L1 computes t1=s-1 (s>=1).
// Wave roles (grp=w>>2): 0: L0 in-proj (xT), 1: L0 recur (h0buf),
//                        2: L1 in-proj (h0buf), 3: L1 recur (h1buf).
// kbase=(w&3)*128 -> each gemm's K=512 split over 4 waves.
// Lane = batch column (c=1, no act duplication). Each lane: 8 rows x 1 batch,
// k paired into v2f accumulators for v_pk_fma_f32. Acts are chunk-prefetched
// (double-buffered, 16 loads in flight); grp0 prefetches next step's first
// chunk across the grid barrier (xT is immutable -> safe).
extern "C" __global__ void __launch_bounds__(NTHR, 4)
lstm_scan(const float* __restrict__ h0,
          const float* __restrict__ c0,
          const float* __restrict__ Wih,
          const float* __restrict__ Whh,
          const float* __restrict__ bih,
          const float* __restrict__ bhh,
          const float* __restrict__ xT,
          float* __restrict__ out,
          float* __restrict__ h0buf,   // [2][512][64]
          float* __restrict__ h1buf,   // [2][512][64]
          unsigned* __restrict__ gbar,
          unsigned* __restrict__ groot)
{
    __shared__ __align__(16) float red[16][8][64];   // 32 KB
    __shared__ __align__(16) float wlds[16][8][128]; // 64 KB (per-wave slices)

    const int tid  = threadIdx.x;
    const int lane = tid & 63;                                   // batch
    const int w    = __builtin_amdgcn_readfirstlane(tid >> 6);   // wave 0..15
    const int bid  = blockIdx.x;
    // XCD-bijective unit swizzle: XCD (bid&7) owns units [ (bid&7)*64, +64 )
    const int vb   = ((bid & 7) << 5) | (bid >> 3);
    const int hk0  = vb << 1;

    const int kbase = (w & 3) << 7;   // 0,128,256,384
    const int grp   = w >> 2;         // 0..3

    const float* Wbase;
    if      (grp == 0) Wbase = Wih;
    else if (grp == 1) Wbase = Whh;
    else if (grp == 2) Wbase = Wih + (size_t)G4 * HH;
    else               Wbase = Whh + (size_t)G4 * HH;

    // Stage this wave's weight slice into LDS once: 8 rows x 128 floats.
    #pragma unroll
    for (int rr = 0; rr < 8; ++rr) {
        const int row = ((rr >> 1) << 9) + hk0 + (rr & 1);
        const float* src = Wbase + (size_t)row * HH + kbase;
        wlds[w][rr][lane]      = src[lane];
        wlds[w][rr][lane + 64] = src[lane + 64];
    }

    float creg[2] = {0.f, 0.f};  // wave0: L0 c-state; wave1: L1 c-state
    float bs[8];
    if (w == 0) {
        #pragma unroll
        for (int u = 0; u < 2; ++u) {
            const int hk = hk0 + u;
            store_coh(&h0buf[hk * BB + lane], h0[(size_t)lane * HH + hk]);
            creg[u] = c0[(size_t)lane * HH + hk];
        }
        #pragma unroll
        for (int rr = 0; rr < 8; ++rr) {
            const int row = ((rr >> 1) << 9) + hk0 + (rr & 1);
            bs[rr] = bih[row] + bhh[row];
        }
    } else if (w == 1) {
        #pragma unroll
        for (int u = 0; u < 2; ++u) {
            const int hk = hk0 + u;
            store_coh(&h1buf[hk * BB + lane], h0[(size_t)(BB + lane) * HH + hk]);
            creg[u] = c0[(size_t)(BB + lane) * HH + hk];
        }
        #pragma unroll
        for (int rr = 0; rr < 8; ++rr) {
            const int row = ((rr >> 1) << 9) + hk0 + (rr & 1);
            bs[rr] = bih[G4 + row] + bhh[G4 + row];
        }
    }

    // wave-uniform LDS weight base for this wave's 8 rows x 128 k
    const float* wl = &wlds[w][0][0];

    float ca[16], cb[16];
    const float* actp_pref = nullptr;
    if (grp == 0) {
        // prefetch step-0 chunk 0 before the initial barrier (xT immutable)
        actp_pref = xT + (size_t)kbase * BB + lane;
        LOADC(ca, actp_pref, 0);
    }

    unsigned barIdx = 0;
    grid_barrier(gbar, groot, barIdx, bid); ++barIdx;

    for (int s = 0; s <= TT; ++s) {
        const float* actp;
        if (grp == 0) {
            actp = actp_pref;            // chunk 0 already in ca
        } else if (grp <= 2) {
            actp = h0buf + (size_t)(s & 1) * KH + (size_t)kbase * BB + lane;
            LOADC(ca, actp, 0);
        } else {
            actp = h1buf + (size_t)((s + 1) & 1) * KH + (size_t)kbase * BB + lane;
            LOADC(ca, actp, 0);
        }

        v2f acc2[8];
        #pragma unroll
        for (int rr = 0; rr < 8; ++rr) acc2[rr] = (v2f){0.f, 0.f};

        LOADC(cb, actp,  16);
        FMAC(ca, 0);
        LOADC(ca, actp,  32);
        FMAC(cb, 16);
        LOADC(cb, actp,  48);
        FMAC(ca, 32);
        LOADC(ca, actp,  64);
        FMAC(cb, 48);
        LOADC(cb, actp,  80);
        FMAC(ca, 64);
        LOADC(ca, actp,  96);
        FMAC(cb, 80);
        LOADC(cb, actp, 112);
        FMAC(ca, 96);
        FMAC(cb, 112);

        if (grp == 0) {
            // prefetch next step's first chunk across the barrier
            const int tn = (s + 1 < TT) ? (s + 1) : (TT - 1);
            actp_pref = xT + (size_t)tn * KH + (size_t)kbase * BB + lane;
            LOADC(ca, actp_pref, 0);
        }

        #pragma unroll
        for (int rr = 0; rr < 8; ++rr)
            red[w][rr][lane] = acc2[rr].x + acc2[rr].y;
        __syncthreads();

        if (w == 0) {
            if (s < TT) {   // layer 0, t0 = s
                float g[8];
                #pragma unroll
                for (int rr = 0; rr < 8; ++rr) {
                    float t = red[0][rr][lane] + red[1][rr][lane]
                            + red[2][rr][lane] + red[3][rr][lane]
                            + red[4][rr][lane] + red[5][rr][lane]
                            + red[6][rr][lane] + red[7][rr][lane];
                    g[rr] = bs[rr] + t;
                }
                #pragma unroll
                for (int u = 0; u < 2; ++u) {
                    const float ig = sigm(g[0 + u]);
                    const float fg = sigm(g[2 + u]);
                    const float gg = tanh_fast(g[4 + u]);
                    const float og = sigm(g[6 + u]);
                    const float cn = fg * creg[u] + ig * gg;
                    const float hn = og * tanh_fast(cn);
                    creg[u] = cn;
                    const int hk = hk0 + u;
                    store_coh(&h0buf[(size_t)((s + 1) & 1) * KH + hk * BB + lane], hn);
                    if (s == TT - 1) {
                        out[HN_OFF + (size_t)lane * HH + hk] = hn;
                        out[CN_OFF + (size_t)lane * HH + hk] = cn;
                    }
                }
            }
        } else if (w == 1) {
            if (s >= 1) {   // layer 1, t1 = s-1
                const int t1 = s - 1;
                float g[8];
                #pragma unroll
                for (int rr = 0; rr < 8; ++rr) {
                    float t = red[8][rr][lane]  + red[9][rr][lane]
                            + red[10][rr][lane] + red[11][rr][lane]
                            + red[12][rr][lane] + red[13][rr][lane]
                            + red[14][rr][lane] + red[15][rr][lane];
                    g[rr] = bs[rr] + t;
                }
                float hn2[2], cn2[2];
                #pragma unroll
                for (int u = 0; u < 2; ++u) {
                    const float ig = sigm(g[0 + u]);
                    const float fg = sigm(g[2 + u]);
                    const float gg = tanh_fast(g[4 + u]);
                    const float og = sigm(g[6 + u]);
                    const float cn = fg * creg[u] + ig * gg;
                    const float hn = og * tanh_fast(cn);
                    creg[u] = cn;
                    cn2[u] = cn; hn2[u] = hn;
                    const int hk = hk0 + u;
                    store_coh(&h1buf[(size_t)(s & 1) * KH + hk * BB + lane], hn);
                }
                // coalescable float2 store of the sequence output
                *(float2*)&out[(size_t)t1 * BB * HH + (size_t)lane * HH + hk0] =
                    make_float2(hn2[0], hn2[1]);
                if (t1 == TT - 1) {
                    *(float2*)&out[HN_OFF + (size_t)(BB + lane) * HH + hk0] =
                        make_float2(hn2[0], hn2[1]);
                    *(float2*)&out[CN_OFF + (size_t)(BB + lane) * HH + hk0] =
                        make_float2(cn2[0], cn2[1]);
                }
            }
        }
        grid_barrier(gbar, groot, barIdx, bid); ++barIdx;
    }
}

// ---------------------------------------------------------------------------
extern "C" void kernel_launch(void* const* d_in, const int* in_sizes, int n_in,
                              void* d_out, int out_size, void* d_ws, size_t ws_size,
                              hipStream_t stream)
{
    (void)in_sizes; (void)n_in; (void)out_size; (void)ws_size;
    const float* x   = (const float*)d_in[0];
    const float* h0  = (const float*)d_in[1];
    const float* c0  = (const float*)d_in[2];
    const float* Wih = (const float*)d_in[3];
    const float* Whh = (const float*)d_in[4];
    const float* bih = (const float*)d_in[5];
    const float* bhh = (const float*)d_in[6];
    float* out = (float*)d_out;

    // ws: xT [T][512][64] (128 MB) | h0buf [2][512][64] | h1buf | barrier ctrs
    float* xT    = (float*)d_ws;
    float* h0buf = xT + (size_t)TT * KH;
    float* h1buf = h0buf + (size_t)2 * KH;
    unsigned* gbar  = (unsigned*)(h1buf + (size_t)2 * KH);
    unsigned* groot = gbar + 256;

    hipMemsetAsync(gbar, 0, (256 + 64) * sizeof(unsigned), stream);

    xpose<<<dim3(TT, 8), 256, 0, stream>>>(x, xT);

    void* args[] = {(void*)&h0, (void*)&c0, (void*)&Wih, (void*)&Whh,
                    (void*)&bih, (void*)&bhh, (void*)&xT, (void*)&out,
                    (void*)&h0buf, (void*)&h1buf, (void*)&gbar, (void*)&groot};
    hipLaunchCooperativeKernel((void*)lstm_scan, dim3(NBLK), dim3(NTHR),
                               args, 0, stream);
}

// Round 5
// 14989.380 us; speedup vs baseline: 35.9463x; 35.9463x over previous
//
#include <hip/hip_runtime.h>
#include <math.h>

#define TT 1024
#define BB 64
#define HH 512
#define G4 2048            // 4*HH
#define NBLK 256
#define NTHR 1024          // 16 waves
#define KH (HH * BB)       // one [512][64] slab = 32768 elems

// out layout: seq [T][B][H] | h_n [L][B][H] | c_n [L][B][H]
#define HN_OFF ((size_t)TT * BB * HH)
#define CN_OFF (HN_OFF + (size_t)2 * BB * HH)

typedef float v2f __attribute__((ext_vector_type(2)));

__device__ inline float sigm(float v) {
    return 1.0f / (1.0f + __expf(-v));
}
__device__ inline float tanh_fast(float v) {
    const float e = __expf(2.0f * v);
    return 1.0f - 2.0f / (e + 1.0f);
}

// Coherent store: lands at the L3 coherence point so other XCDs can see it
// after their per-step acquire fence.
__device__ inline void store_coh(float* p, float v) {
    __hip_atomic_store(p, v, __ATOMIC_RELAXED, __HIP_MEMORY_SCOPE_AGENT);
}

// ---------------- phase A: transpose x [T][B][K] -> xT [T][K][B] ------------
extern "C" __global__ void __launch_bounds__(256)
xpose(const float* __restrict__ x, float* __restrict__ xT)
{
    __shared__ float tile[64][65];
    const int t   = blockIdx.x;
    const int kc  = blockIdx.y << 6;
    const int tid = threadIdx.x;

    const int kk = tid & 63;
    const int b0 = tid >> 6;
    const float* xp = x + (size_t)t * BB * HH;
    #pragma unroll
    for (int i = 0; i < 16; ++i) {
        const int b = b0 + (i << 2);
        tile[b][kk] = xp[(size_t)b * HH + kc + kk];
    }
    __syncthreads();
    const int b  = tid & 63;
    const int k0 = tid >> 6;
    float* xo = xT + (size_t)t * KH + (size_t)kc * BB;
    #pragma unroll
    for (int i = 0; i < 16; ++i) {
        const int kl = k0 + (i << 2);
        xo[kl * BB + b] = tile[b][kl];
    }
}

// ---------------- grid barrier: relaxed atomics, ONE buffer_inv per step ----
__device__ inline void grid_barrier(unsigned* gbar, unsigned* groot,
                                    unsigned barIdx, int bid)
{
    __syncthreads();   // rendezvous + drains every wave's vmcnt (h-stores done)
    if (threadIdx.x == 0) {
        const int g = bid & 15;
        const unsigned old = __hip_atomic_fetch_add(
            &gbar[g * 16], 1u, __ATOMIC_RELAXED, __HIP_MEMORY_SCOPE_AGENT);
        if (old == barIdx * 16u + 15u) {
            __hip_atomic_fetch_add(groot, 1u, __ATOMIC_RELAXED,
                                   __HIP_MEMORY_SCOPE_AGENT);
        }
        const unsigned tgt = (barIdx + 1u) * 16u;
        while (__hip_atomic_load(groot, __ATOMIC_RELAXED,
                                 __HIP_MEMORY_SCOPE_AGENT) < tgt) {
            __builtin_amdgcn_s_sleep(1);
        }
        // single L1+L2 invalidate for this CU/XCD, per step
        __builtin_amdgcn_fence(__ATOMIC_ACQUIRE, "agent");
    }
    __syncthreads();
}

// ---------------- phase B: pipelined persistent scan ------------------------
// 256 blocks x 16 waves. Block owns 2 hidden units per layer (8 gate rows each),
// chosen via an XCD-bijective swizzle so one XCD owns 64 contiguous units.
// Step s: L0 computes t0=s (s<TT), L1 computes t1=s-1 (s>=1).
// Wave roles (grp=w>>2): 0: L0 in-proj (xT), 1: L0 recur (h0buf),
//                        2: L1 in-proj (h0buf), 3: L1 recur (h1buf).
// kbase=(w&3)*128 -> each gemm's K=512 split over 4 waves.
// Lane = batch (no act duplication; R1's proven load pattern). Each lane:
// 8 rows x 1 batch, consecutive k paired into v2f accs for v_pk_fma_f32.
extern "C" __global__ void __launch_bounds__(NTHR)
lstm_scan(const float* __restrict__ h0,
          const float* __restrict__ c0,
          const float* __restrict__ Wih,
          const float* __restrict__ Whh,
          const float* __restrict__ bih,
          const float* __restrict__ bhh,
          const float* __restrict__ xT,
          float* __restrict__ out,
          float* __restrict__ h0buf,   // [2][512][64]
          float* __restrict__ h1buf,   // [2][512][64]
          unsigned* __restrict__ gbar,
          unsigned* __restrict__ groot)
{
    __shared__ __align__(16) float red[16][8][64];   // 32 KB
    __shared__ __align__(16) float wlds[16][8][128]; // 64 KB (per-wave slices)

    const int tid  = threadIdx.x;
    const int lane = tid & 63;                                   // batch
    const int w    = __builtin_amdgcn_readfirstlane(tid >> 6);   // wave 0..15
    const int bid  = blockIdx.x;
    // XCD-bijective unit swizzle: XCD (bid&7) owns units [ (bid&7)*64, +64 )
    const int vb   = ((bid & 7) << 5) | (bid >> 3);
    const int hk0  = vb << 1;

    const int kbase = (w & 3) << 7;   // 0,128,256,384
    const int grp   = w >> 2;         // 0..3

    const float* Wbase;
    if      (grp == 0) Wbase = Wih;
    else if (grp == 1) Wbase = Whh;
    else if (grp == 2) Wbase = Wih + (size_t)G4 * HH;
    else               Wbase = Whh + (size_t)G4 * HH;

    // Stage this wave's weight slice into LDS once: 8 rows x 128 floats.
    #pragma unroll
    for (int rr = 0; rr < 8; ++rr) {
        const int row = ((rr >> 1) << 9) + hk0 + (rr & 1);
        const float* src = Wbase + (size_t)row * HH + kbase;
        wlds[w][rr][lane]      = src[lane];
        wlds[w][rr][lane + 64] = src[lane + 64];
    }

    float creg[2] = {0.f, 0.f};  // wave0: L0 c-state; wave1: L1 c-state
    float bs[8];
    if (w == 0) {
        #pragma unroll
        for (int u = 0; u < 2; ++u) {
            const int hk = hk0 + u;
            store_coh(&h0buf[hk * BB + lane], h0[(size_t)lane * HH + hk]);
            creg[u] = c0[(size_t)lane * HH + hk];
        }
        #pragma unroll
        for (int rr = 0; rr < 8; ++rr) {
            const int row = ((rr >> 1) << 9) + hk0 + (rr & 1);
            bs[rr] = bih[row] + bhh[row];
        }
    } else if (w == 1) {
        #pragma unroll
        for (int u = 0; u < 2; ++u) {
            const int hk = hk0 + u;
            store_coh(&h1buf[hk * BB + lane], h0[(size_t)(BB + lane) * HH + hk]);
            creg[u] = c0[(size_t)(BB + lane) * HH + hk];
        }
        #pragma unroll
        for (int rr = 0; rr < 8; ++rr) {
            const int row = ((rr >> 1) << 9) + hk0 + (rr & 1);
            bs[rr] = bih[G4 + row] + bhh[G4 + row];
        }
    }

    unsigned barIdx = 0;
    grid_barrier(gbar, groot, barIdx, bid); ++barIdx;

    const float* wl = &wlds[w][0][0];   // [8][128], wave-uniform base

    for (int s = 0; s <= TT; ++s) {
        const float* act;
        if (grp == 0) {
            const int t0 = (s < TT) ? s : (TT - 1);
            act = xT + (size_t)t0 * KH + (size_t)kbase * BB;
        } else if (grp <= 2) {
            act = h0buf + (size_t)(s & 1) * KH + (size_t)kbase * BB;
        } else {
            act = h1buf + (size_t)((s + 1) & 1) * KH + (size_t)kbase * BB;
        }

        v2f acc2[8];
        #pragma unroll
        for (int rr = 0; rr < 8; ++rr) acc2[rr] = (v2f){0.f, 0.f};

        #pragma unroll 2
        for (int j = 0; j < 128; j += 4) {
            const float a0 = act[(j + 0) * BB + lane];
            const float a1 = act[(j + 1) * BB + lane];
            const float a2 = act[(j + 2) * BB + lane];
            const float a3 = act[(j + 3) * BB + lane];
            const v2f aA = {a0, a1};
            const v2f aB = {a2, a3};
            #pragma unroll
            for (int rr = 0; rr < 8; ++rr) {
                const float4 wv = *(const float4*)(wl + rr * 128 + j);
                acc2[rr] = __builtin_elementwise_fma(aA, (v2f){wv.x, wv.y}, acc2[rr]);
                acc2[rr] = __builtin_elementwise_fma(aB, (v2f){wv.z, wv.w}, acc2[rr]);
            }
        }

        #pragma unroll
        for (int rr = 0; rr < 8; ++rr)
            red[w][rr][lane] = acc2[rr].x + acc2[rr].y;
        __syncthreads();

        if (w == 0) {
            if (s < TT) {   // layer 0, t0 = s
                float g[8];
                #pragma unroll
                for (int rr = 0; rr < 8; ++rr) {
                    float t = red[0][rr][lane] + red[1][rr][lane]
                            + red[2][rr][lane] + red[3][rr][lane]
                            + red[4][rr][lane] + red[5][rr][lane]
                            + red[6][rr][lane] + red[7][rr][lane];
                    g[rr] = bs[rr] + t;
                }
                float hn2[2], cn2[2];
                #pragma unroll
                for (int u = 0; u < 2; ++u) {
                    const float ig = sigm(g[0 + u]);
                    const float fg = sigm(g[2 + u]);
                    const float gg = tanh_fast(g[4 + u]);
                    const float og = sigm(g[6 + u]);
                    const float cn = fg * creg[u] + ig * gg;
                    const float hn = og * tanh_fast(cn);
                    creg[u] = cn;
                    cn2[u] = cn; hn2[u] = hn;
                    const int hk = hk0 + u;
                    store_coh(&h0buf[(size_t)((s + 1) & 1) * KH + hk * BB + lane], hn);
                }
                if (s == TT - 1) {
                    *(float2*)&out[HN_OFF + (size_t)lane * HH + hk0] =
                        make_float2(hn2[0], hn2[1]);
                    *(float2*)&out[CN_OFF + (size_t)lane * HH + hk0] =
                        make_float2(cn2[0], cn2[1]);
                }
            }
        } else if (w == 1) {
            if (s >= 1) {   // layer 1, t1 = s-1
                const int t1 = s - 1;
                float g[8];
                #pragma unroll
                for (int rr = 0; rr < 8; ++rr) {
                    float t = red[8][rr][lane]  + red[9][rr][lane]
                            + red[10][rr][lane] + red[11][rr][lane]
                            + red[12][rr][lane] + red[13][rr][lane]
                            + red[14][rr][lane] + red[15][rr][lane];
                    g[rr] = bs[rr] + t;
                }
                float hn2[2], cn2[2];
                #pragma unroll
                for (int u = 0; u < 2; ++u) {
                    const float ig = sigm(g[0 + u]);
                    const float fg = sigm(g[2 + u]);
                    const float gg = tanh_fast(g[4 + u]);
                    const float og = sigm(g[6 + u]);
                    const float cn = fg * creg[u] + ig * gg;
                    const float hn = og * tanh_fast(cn);
                    creg[u] = cn;
                    cn2[u] = cn; hn2[u] = hn;
                    const int hk = hk0 + u;
                    store_coh(&h1buf[(size_t)(s & 1) * KH + hk * BB + lane], hn);
                }
                // coalescable float2 store of the sequence output
                *(float2*)&out[(size_t)t1 * BB * HH + (size_t)lane * HH + hk0] =
                    make_float2(hn2[0], hn2[1]);
                if (t1 == TT - 1) {
                    *(float2*)&out[HN_OFF + (size_t)(BB + lane) * HH + hk0] =
                        make_float2(hn2[0], hn2[1]);
                    *(float2*)&out[CN_OFF + (size_t)(BB + lane) * HH + hk0] =
                        make_float2(cn2[0], cn2[1]);
                }
            }
        }
        grid_barrier(gbar, groot, barIdx, bid); ++barIdx;
    }
}

// ---------------------------------------------------------------------------
extern "C" void kernel_launch(void* const* d_in, const int* in_sizes, int n_in,
                              void* d_out, int out_size, void* d_ws, size_t ws_size,
                              hipStream_t stream)
{
    (void)in_sizes; (void)n_in; (void)out_size; (void)ws_size;
    const float* x   = (const float*)d_in[0];
    const float* h0  = (const float*)d_in[1];
    const float* c0  = (const float*)d_in[2];
    const float* Wih = (const float*)d_in[3];
    const float* Whh = (const float*)d_in[4];
    const float* bih = (const float*)d_in[5];
    const float* bhh = (const float*)d_in[6];
    float* out = (float*)d_out;

    // ws: xT [T][512][64] (128 MB) | h0buf [2][512][64] | h1buf | barrier ctrs
    float* xT    = (float*)d_ws;
    float* h0buf = xT + (size_t)TT * KH;
    float* h1buf = h0buf + (size_t)2 * KH;
    unsigned* gbar  = (unsigned*)(h1buf + (size_t)2 * KH);
    unsigned* groot = gbar + 256;

    hipMemsetAsync(gbar, 0, (256 + 64) * sizeof(unsigned), stream);

    xpose<<<dim3(TT, 8), 256, 0, stream>>>(x, xT);

    void* args[] = {(void*)&h0, (void*)&c0, (void*)&Wih, (void*)&Whh,
                    (void*)&bih, (void*)&bhh, (void*)&xT, (void*)&out,
                    (void*)&h0buf, (void*)&h1buf, (void*)&gbar, (void*)&groot};
    hipLaunchCooperativeKernel((void*)lstm_scan, dim3(NBLK), dim3(NTHR),
                               args, 0, stream);
}

// Round 6
// 14235.477 us; speedup vs baseline: 37.8499x; 1.0530x over previous
//
#include <hip/hip_runtime.h>
#include <math.h>

#define TT 1024
#define BB 64
#define HH 512
#define G4 2048            // 4*HH
#define NBLK 256
#define NTHR 1024          // 16 waves
#define KHU (256 * 64)     // one packed-bf16 slab: [256 k-pairs][64 b] uints

// out layout: seq [T][B][H] | h_n [L][B][H] | c_n [L][B][H]
#define HN_OFF ((size_t)TT * BB * HH)
#define CN_OFF (HN_OFF + (size_t)2 * BB * HH)

typedef float v2f __attribute__((ext_vector_type(2)));

__device__ inline float sigm(float v) {
    return 1.0f / (1.0f + __expf(-v));
}
__device__ inline float tanh_fast(float v) {
    const float e = __expf(2.0f * v);
    return 1.0f - 2.0f / (e + 1.0f);
}

// round-to-nearest-even f32 -> bf16 (as low 16 bits of a uint)
__device__ inline unsigned bf16rn(float f) {
    const unsigned x = __float_as_uint(f);
    return (x + 0x7FFFu + ((x >> 16) & 1u)) >> 16;
}
__device__ inline unsigned pack2(float lo, float hi) {
    return bf16rn(lo) | (bf16rn(hi) << 16);
}

// Coherent store: lands at the L3 coherence point so other XCDs can see it
// after their per-step acquire fence.
__device__ inline void store_coh_u(unsigned* p, unsigned v) {
    __hip_atomic_store(p, v, __ATOMIC_RELAXED, __HIP_MEMORY_SCOPE_AGENT);
}

// ------- phase A: transpose+pack x [T][B][K] f32 -> xT [T][K/2][B] bf16x2 ----
extern "C" __global__ void __launch_bounds__(256)
xpose(const float* __restrict__ x, unsigned* __restrict__ xT)
{
    __shared__ float tile[64][65];
    const int t   = blockIdx.x;
    const int kc  = blockIdx.y << 6;   // 64-k chunk
    const int tid = threadIdx.x;

    const int kk = tid & 63;
    const int b0 = tid >> 6;
    const float* xp = x + (size_t)t * BB * HH;
    #pragma unroll
    for (int i = 0; i < 16; ++i) {
        const int b = b0 + (i << 2);
        tile[b][kk] = xp[(size_t)b * HH + kc + kk];
    }
    __syncthreads();
    const int b   = tid & 63;
    const int kp0 = tid >> 6;          // 0..3
    unsigned* xo = xT + (size_t)t * KHU + (size_t)(kc >> 1) * 64;
    #pragma unroll
    for (int i = 0; i < 8; ++i) {
        const int kp = kp0 + (i << 2); // 0..31 local k-pair
        xo[kp * 64 + b] = pack2(tile[b][2 * kp], tile[b][2 * kp + 1]);
    }
}

// ---------------- grid barrier: relaxed atomics, ONE buffer_inv per step ----
__device__ inline void grid_barrier(unsigned* gbar, unsigned* groot,
                                    unsigned barIdx, int bid)
{
    __syncthreads();   // rendezvous + drains every wave's vmcnt (h-stores done)
    if (threadIdx.x == 0) {
        const int g = bid & 15;
        const unsigned old = __hip_atomic_fetch_add(
            &gbar[g * 16], 1u, __ATOMIC_RELAXED, __HIP_MEMORY_SCOPE_AGENT);
        if (old == barIdx * 16u + 15u) {
            __hip_atomic_fetch_add(groot, 1u, __ATOMIC_RELAXED,
                                   __HIP_MEMORY_SCOPE_AGENT);
        }
        const unsigned tgt = (barIdx + 1u) * 16u;
        while (__hip_atomic_load(groot, __ATOMIC_RELAXED,
                                 __HIP_MEMORY_SCOPE_AGENT) < tgt) {
            __builtin_amdgcn_s_sleep(1);
        }
        // single L1+L2 invalidate for this CU/XCD, per step
        __builtin_amdgcn_fence(__ATOMIC_ACQUIRE, "agent");
    }
    __syncthreads();
}

// ---------------- phase B: pipelined persistent scan ------------------------
// 256 blocks x 16 waves. Block owns 2 hidden units per layer (8 gate rows each),
// chosen via an XCD-bijective swizzle so one XCD owns 64 contiguous units.
// Step s: L0 computes t0=s (s<TT), L1 computes t1=s-1 (s>=1).
// Wave roles (grp=w>>2): 0: L0 in-proj (xT), 1: L0 recur (h0buf),
//                        2: L1 in-proj (h0buf), 3: L1 recur (h1buf).
// kbase=(w&3)*128 -> each gemm's K=512 split over 4 waves.
// Activations are packed bf16 pairs [k/2][64b] (uint; low ushort = even k):
// halves the dominant act L1/L2 stream. Weights/accumulators/c-state/red are
// exact f32. Lane = batch; k-pairs map 1:1 onto v_pk_fma_f32 accumulators.
extern "C" __global__ void __launch_bounds__(NTHR)
lstm_scan(const float* __restrict__ h0,
          const float* __restrict__ c0,
          const float* __restrict__ Wih,
          const float* __restrict__ Whh,
          const float* __restrict__ bih,
          const float* __restrict__ bhh,
          const unsigned* __restrict__ xT,
          float* __restrict__ out,
          unsigned* __restrict__ h0buf,   // [2][256][64] bf16x2
          unsigned* __restrict__ h1buf,   // [2][256][64] bf16x2
          unsigned* __restrict__ gbar,
          unsigned* __restrict__ groot)
{
    __shared__ __align__(16) float red[16][8][64];   // 32 KB
    __shared__ __align__(16) float wlds[16][8][128]; // 64 KB (per-wave slices)

    const int tid  = threadIdx.x;
    const int lane = tid & 63;                                   // batch
    const int w    = __builtin_amdgcn_readfirstlane(tid >> 6);   // wave 0..15
    const int bid  = blockIdx.x;
    // XCD-bijective unit swizzle: XCD (bid&7) owns units [ (bid&7)*64, +64 )
    const int vb   = ((bid & 7) << 5) | (bid >> 3);
    const int hk0  = vb << 1;

    const int kbase = (w & 3) << 7;   // 0,128,256,384 (k units)
    const int grp   = w >> 2;         // 0..3

    const float* Wbase;
    if      (grp == 0) Wbase = Wih;
    else if (grp == 1) Wbase = Whh;
    else if (grp == 2) Wbase = Wih + (size_t)G4 * HH;
    else               Wbase = Whh + (size_t)G4 * HH;

    // Stage this wave's weight slice into LDS once: 8 rows x 128 floats.
    #pragma unroll
    for (int rr = 0; rr < 8; ++rr) {
        const int row = ((rr >> 1) << 9) + hk0 + (rr & 1);
        const float* src = Wbase + (size_t)row * HH + kbase;
        wlds[w][rr][lane]      = src[lane];
        wlds[w][rr][lane + 64] = src[lane + 64];
    }

    float creg[2] = {0.f, 0.f};  // wave0: L0 c-state; wave1: L1 c-state
    float bs[8];
    if (w == 0) {
        store_coh_u(&h0buf[vb * 64 + lane],
                    pack2(h0[(size_t)lane * HH + hk0],
                          h0[(size_t)lane * HH + hk0 + 1]));
        creg[0] = c0[(size_t)lane * HH + hk0];
        creg[1] = c0[(size_t)lane * HH + hk0 + 1];
        #pragma unroll
        for (int rr = 0; rr < 8; ++rr) {
            const int row = ((rr >> 1) << 9) + hk0 + (rr & 1);
            bs[rr] = bih[row] + bhh[row];
        }
    } else if (w == 1) {
        store_coh_u(&h1buf[vb * 64 + lane],
                    pack2(h0[(size_t)(BB + lane) * HH + hk0],
                          h0[(size_t)(BB + lane) * HH + hk0 + 1]));
        creg[0] = c0[(size_t)(BB + lane) * HH + hk0];
        creg[1] = c0[(size_t)(BB + lane) * HH + hk0 + 1];
        #pragma unroll
        for (int rr = 0; rr < 8; ++rr) {
            const int row = ((rr >> 1) << 9) + hk0 + (rr & 1);
            bs[rr] = bih[G4 + row] + bhh[G4 + row];
        }
    }

    unsigned barIdx = 0;
    grid_barrier(gbar, groot, barIdx, bid); ++barIdx;

    const float* wl = &wlds[w][0][0];   // [8][128], wave-uniform base

    for (int s = 0; s <= TT; ++s) {
        const unsigned* actu;   // this wave's k-quarter, packed pairs, +lane
        if (grp == 0) {
            const int t0 = (s < TT) ? s : (TT - 1);
            actu = xT + (size_t)t0 * KHU + kbase * 32;
        } else if (grp <= 2) {
            actu = h0buf + (size_t)(s & 1) * KHU + kbase * 32;
        } else {
            actu = h1buf + (size_t)((s + 1) & 1) * KHU + kbase * 32;
        }

        v2f acc2[8];
        #pragma unroll
        for (int rr = 0; rr < 8; ++rr) acc2[rr] = (v2f){0.f, 0.f};

        #pragma unroll 2
        for (int j = 0; j < 128; j += 4) {
            const unsigned u0 = actu[(j >> 1) * 64 + lane];
            const unsigned u1 = actu[(j >> 1) * 64 + 64 + lane];
            const v2f aA = { __uint_as_float(u0 << 16),
                             __uint_as_float(u0 & 0xFFFF0000u) };
            const v2f aB = { __uint_as_float(u1 << 16),
                             __uint_as_float(u1 & 0xFFFF0000u) };
            #pragma unroll
            for (int rr = 0; rr < 8; ++rr) {
                const float4 wv = *(const float4*)(wl + rr * 128 + j);
                acc2[rr] = __builtin_elementwise_fma(aA, (v2f){wv.x, wv.y}, acc2[rr]);
                acc2[rr] = __builtin_elementwise_fma(aB, (v2f){wv.z, wv.w}, acc2[rr]);
            }
        }

        #pragma unroll
        for (int rr = 0; rr < 8; ++rr)
            red[w][rr][lane] = acc2[rr].x + acc2[rr].y;
        __syncthreads();

        if (w == 0) {
            if (s < TT) {   // layer 0, t0 = s
                float g[8];
                #pragma unroll
                for (int rr = 0; rr < 8; ++rr) {
                    float t = red[0][rr][lane] + red[1][rr][lane]
                            + red[2][rr][lane] + red[3][rr][lane]
                            + red[4][rr][lane] + red[5][rr][lane]
                            + red[6][rr][lane] + red[7][rr][lane];
                    g[rr] = bs[rr] + t;
                }
                float hn2[2], cn2[2];
                #pragma unroll
                for (int u = 0; u < 2; ++u) {
                    const float ig = sigm(g[0 + u]);
                    const float fg = sigm(g[2 + u]);
                    const float gg = tanh_fast(g[4 + u]);
                    const float og = sigm(g[6 + u]);
                    const float cn = fg * creg[u] + ig * gg;
                    const float hn = og * tanh_fast(cn);
                    creg[u] = cn;
                    cn2[u] = cn; hn2[u] = hn;
                }
                store_coh_u(&h0buf[(size_t)((s + 1) & 1) * KHU + vb * 64 + lane],
                            pack2(hn2[0], hn2[1]));
                if (s == TT - 1) {
                    *(float2*)&out[HN_OFF + (size_t)lane * HH + hk0] =
                        make_float2(hn2[0], hn2[1]);
                    *(float2*)&out[CN_OFF + (size_t)lane * HH + hk0] =
                        make_float2(cn2[0], cn2[1]);
                }
            }
        } else if (w == 1) {
            if (s >= 1) {   // layer 1, t1 = s-1
                const int t1 = s - 1;
                float g[8];
                #pragma unroll
                for (int rr = 0; rr < 8; ++rr) {
                    float t = red[8][rr][lane]  + red[9][rr][lane]
                            + red[10][rr][lane] + red[11][rr][lane]
                            + red[12][rr][lane] + red[13][rr][lane]
                            + red[14][rr][lane] + red[15][rr][lane];
                    g[rr] = bs[rr] + t;
                }
                float hn2[2], cn2[2];
                #pragma unroll
                for (int u = 0; u < 2; ++u) {
                    const float ig = sigm(g[0 + u]);
                    const float fg = sigm(g[2 + u]);
                    const float gg = tanh_fast(g[4 + u]);
                    const float og = sigm(g[6 + u]);
                    const float cn = fg * creg[u] + ig * gg;
                    const float hn = og * tanh_fast(cn);
                    creg[u] = cn;
                    cn2[u] = cn; hn2[u] = hn;
                }
                store_coh_u(&h1buf[(size_t)(s & 1) * KHU + vb * 64 + lane],
                            pack2(hn2[0], hn2[1]));
                // coalescable float2 store of the sequence output
                *(float2*)&out[(size_t)t1 * BB * HH + (size_t)lane * HH + hk0] =
                    make_float2(hn2[0], hn2[1]);
                if (t1 == TT - 1) {
                    *(float2*)&out[HN_OFF + (size_t)(BB + lane) * HH + hk0] =
                        make_float2(hn2[0], hn2[1]);
                    *(float2*)&out[CN_OFF + (size_t)(BB + lane) * HH + hk0] =
                        make_float2(cn2[0], cn2[1]);
                }
            }
        }
        grid_barrier(gbar, groot, barIdx, bid); ++barIdx;
    }
}

// ---------------------------------------------------------------------------
extern "C" void kernel_launch(void* const* d_in, const int* in_sizes, int n_in,
                              void* d_out, int out_size, void* d_ws, size_t ws_size,
                              hipStream_t stream)
{
    (void)in_sizes; (void)n_in; (void)out_size; (void)ws_size;
    const float* x   = (const float*)d_in[0];
    const float* h0  = (const float*)d_in[1];
    const float* c0  = (const float*)d_in[2];
    const float* Wih = (const float*)d_in[3];
    const float* Whh = (const float*)d_in[4];
    const float* bih = (const float*)d_in[5];
    const float* bhh = (const float*)d_in[6];
    float* out = (float*)d_out;

    // ws: xT packed bf16 [T][256][64] uints (64 MB) | h0buf | h1buf | counters
    unsigned* xT    = (unsigned*)d_ws;
    unsigned* h0buf = xT + (size_t)TT * KHU;
    unsigned* h1buf = h0buf + (size_t)2 * KHU;
    unsigned* gbar  = h1buf + (size_t)2 * KHU;
    unsigned* groot = gbar + 256;

    hipMemsetAsync(gbar, 0, (256 + 64) * sizeof(unsigned), stream);

    xpose<<<dim3(TT, 8), 256, 0, stream>>>(x, xT);

    void* args[] = {(void*)&h0, (void*)&c0, (void*)&Wih, (void*)&Whh,
                    (void*)&bih, (void*)&bhh, (void*)&xT, (void*)&out,
                    (void*)&h0buf, (void*)&h1buf, (void*)&gbar, (void*)&groot};
    hipLaunchCooperativeKernel((void*)lstm_scan, dim3(NBLK), dim3(NTHR),
                               args, 0, stream);
}